// Round 1
// baseline (710.490 us; speedup 1.0000x reference)
//
#include <hip/hip_runtime.h>
#include <math.h>

#define BATCH 8
#define CCH 256
#define HW 40000
#define HW4 (HW / 4)          // 10000 float4 pixels per row
#define KSEL 8000
#define EPS_LN 1e-6f
#define EPS_COS 1e-8f
#define SLICES 40             // blocks per batch for hist/sum passes
#define SLICE_LEN (HW / SLICES)

// ---- workspace layout (uint/float units) ----
// [0)        score    : BATCH*HW floats
// [320000)   contrib  : BATCH*HW floats
// [640000)   hist1    : BATCH*65536 uint
// [1164288)  hist2    : BATCH*65536 uint
// [1688576)  prefix   : 8 uint
// [1688584)  rem1     : 8 uint
// [1688592)  Tkey     : 8 uint
// [1688600)  rem2     : 8 uint
// [1688608)  tie      : 8 uint
// [1688616)  bsums    : 8 float
#define OFF_SCORE   0
#define OFF_CONTRIB 320000
#define OFF_HIST1   640000
#define OFF_HIST2   1164288
#define OFF_PREFIX  1688576
#define OFF_REM1    1688584
#define OFF_TKEY    1688592
#define OFF_REM2    1688600
#define OFF_TIE     1688608
#define OFF_BSUMS   1688616

typedef float v4f __attribute__((ext_vector_type(4)));

__device__ __forceinline__ unsigned int mono_key(float x) {
  unsigned int u = __float_as_uint(x);
  return (u & 0x80000000u) ? ~u : (u | 0x80000000u);
}

// Zero hist1+hist2 (+ bsums). 1048576 uints starting at OFF_HIST1, plus 8 floats.
__global__ __launch_bounds__(256) void zero_kernel(unsigned int* __restrict__ ws) {
  const int n4 = (2 * BATCH * 65536) / 4;  // uint4 count over hist1+hist2
  uint4* p = (uint4*)(ws + OFF_HIST1);
  uint4 z = {0u, 0u, 0u, 0u};
  for (int i = blockIdx.x * blockDim.x + threadIdx.x; i < n4; i += gridDim.x * blockDim.x)
    p[i] = z;
  if (blockIdx.x == 0 && threadIdx.x < BATCH) ws[OFF_BSUMS + threadIdx.x] = 0u;
}

// One thread per 4 consecutive pixels: stream C=256 channels of both tensors,
// nontemporal float4 loads (16 B/lane), emit score (raw sum a^2), contrib
// (1 - cos sim), AND the top-16-bit histogram (hist1 fused here: the keys are
// already in registers, so the old hist1 pass's score re-read + launch go away).
__global__ __launch_bounds__(256) void pixel_stats_kernel(
    const float* __restrict__ A, const float* __restrict__ B,
    float* __restrict__ score, float* __restrict__ contrib,
    unsigned int* __restrict__ ws) {
  int tid = blockIdx.x * blockDim.x + threadIdx.x;
  if (tid >= BATCH * HW4) return;
  int b = tid / HW4;
  int p4 = tid - b * HW4;
  const v4f* a  = (const v4f*)(A + (size_t)b * CCH * HW) + p4;
  const v4f* bb = (const v4f*)(B + (size_t)b * CCH * HW) + p4;

  float sa[4] = {0, 0, 0, 0}, ssa[4] = {0, 0, 0, 0};
  float sb[4] = {0, 0, 0, 0}, ssb[4] = {0, 0, 0, 0}, dab[4] = {0, 0, 0, 0};
#pragma unroll 8
  for (int c = 0; c < CCH; ++c) {
    v4f x = __builtin_nontemporal_load(a + (size_t)c * HW4);
    v4f y = __builtin_nontemporal_load(bb + (size_t)c * HW4);
#pragma unroll
    for (int j = 0; j < 4; ++j) {
      float xs = x[j], ys = y[j];
      sa[j] += xs;
      ssa[j] = fmaf(xs, xs, ssa[j]);
      sb[j] += ys;
      ssb[j] = fmaf(ys, ys, ssb[j]);
      dab[j] = fmaf(xs, ys, dab[j]);
    }
  }

  float scv[4], cov[4];
  const float invC = 1.0f / (float)CCH;
#pragma unroll
  for (int j = 0; j < 4; ++j) {
    scv[j] = ssa[j];
    float mua = sa[j] * invC, mub = sb[j] * invC;
    float cssa = fmaxf(ssa[j] - (float)CCH * mua * mua, 0.f);
    float cssb = fmaxf(ssb[j] - (float)CCH * mub * mub, 0.f);
    float cdot = dab[j] - (float)CCH * mua * mub;
    float siga = sqrtf(cssa / (float)(CCH - 1)) + EPS_LN;
    float sigb = sqrtf(cssb / (float)(CCH - 1)) + EPS_LN;
    float num = cdot / (siga * sigb);
    float na = sqrtf(cssa) / siga;
    float nb = sqrtf(cssb) / sigb;
    cov[j] = 1.0f - num / (fmaxf(na, EPS_COS) * fmaxf(nb, EPS_COS));
  }
  int out = b * HW + p4 * 4;
  *(v4f*)(score + out)   = (v4f){scv[0], scv[1], scv[2], scv[3]};
  *(v4f*)(contrib + out) = (v4f){cov[0], cov[1], cov[2], cov[3]};

  // fused hist1: top 16 bits of the monotone key
  unsigned int* h1 = ws + OFF_HIST1 + (b << 16);
#pragma unroll
  for (int j = 0; j < 4; ++j)
    atomicAdd(&h1[mono_key(scv[j]) >> 16], 1u);
}

// Histogram of low 16 bits among keys whose top16 == prefix[b].
__global__ __launch_bounds__(256) void hist2_kernel(
    const float* __restrict__ score, unsigned int* __restrict__ ws) {
  int b = blockIdx.x / SLICES;
  int sl = blockIdx.x - b * SLICES;
  const float* s = score + b * HW;
  unsigned int pref = ws[OFF_PREFIX + b];
  unsigned int* h = ws + OFF_HIST2 + (b << 16);
  int base = sl * SLICE_LEN;
  for (int i = base + threadIdx.x; i < base + SLICE_LEN; i += 256) {
    unsigned int key = mono_key(s[i]);
    if ((key >> 16) == pref) atomicAdd(&h[key & 0xFFFFu], 1u);
  }
}

// Find, within a 65536-bin histogram, the highest bin index D such that
// count(bins > D) < K <= count(bins >= D). Parallel suffix scan over 1024
// chunk sums (64 bins/chunk), then a 64-iteration serial walk in the chunk.
// phase==0: hist1, K=KSEL -> writes prefix, rem1.
// phase==1: hist2, K=rem1 -> writes Tkey=(prefix<<16)|D, rem2, tie=0.
__global__ __launch_bounds__(1024) void select_kernel(unsigned int* __restrict__ ws,
                                                      int phase) {
  int b = blockIdx.x;
  const unsigned int* h = ws + (phase ? OFF_HIST2 : OFF_HIST1) + (b << 16);
  unsigned int K = phase ? ws[OFF_REM1 + b] : (unsigned int)KSEL;

  __shared__ unsigned int chunk[1024];
  __shared__ unsigned int suf[1024];
  __shared__ unsigned int s_chunk_idx, s_cum_above;
  __shared__ unsigned int bins[64];

  int t = threadIdx.x;
  unsigned int sum = 0;
#pragma unroll 8
  for (int i = 0; i < 64; ++i) sum += h[t * 64 + i];
  chunk[t] = sum;
  suf[t] = sum;
  __syncthreads();
  // Hillis-Steele inclusive suffix scan: suf[t] = sum of chunk[t..1023]
  for (int off = 1; off < 1024; off <<= 1) {
    unsigned int v = (t + off < 1024) ? suf[t + off] : 0u;
    __syncthreads();
    suf[t] += v;
    __syncthreads();
  }
  unsigned int above = (t == 1023) ? 0u : suf[t + 1];
  if (suf[t] >= K && above < K) { s_chunk_idx = (unsigned int)t; s_cum_above = above; }
  __syncthreads();
  if (t < 64) bins[t] = h[s_chunk_idx * 64 + t];
  __syncthreads();
  if (t == 0) {
    unsigned int cum = s_cum_above;
    int d = 63;
    for (; d >= 0; --d) {
      if (cum + bins[d] >= K) break;
      cum += bins[d];
    }
    unsigned int binidx = s_chunk_idx * 64 + (unsigned int)d;
    if (phase == 0) {
      ws[OFF_PREFIX + b] = binidx;
      ws[OFF_REM1 + b] = K - cum;
    } else {
      ws[OFF_TKEY + b] = (ws[OFF_PREFIX + b] << 16) | binidx;
      ws[OFF_REM2 + b] = K - cum;
      ws[OFF_TIE + b] = 0u;
    }
  }
}

// Sum contribs of top-k pixels: all key > T, plus rem2 counted ties at key == T.
__global__ __launch_bounds__(256) void sum_kernel(
    const float* __restrict__ score, const float* __restrict__ contrib,
    unsigned int* __restrict__ ws) {
  int b = blockIdx.x / SLICES;
  int sl = blockIdx.x - b * SLICES;
  const float* s = score + b * HW;
  const float* ct = contrib + b * HW;
  unsigned int T = ws[OFF_TKEY + b];
  unsigned int rem2 = ws[OFF_REM2 + b];

  float partial = 0.f;
  int base = sl * SLICE_LEN;
  for (int i = base + threadIdx.x; i < base + SLICE_LEN; i += 256) {
    unsigned int key = mono_key(s[i]);
    if (key > T) {
      partial += ct[i];
    } else if (key == T) {
      unsigned int old = atomicAdd(&ws[OFF_TIE + b], 1u);
      if (old < rem2) partial += ct[i];
    }
  }

  __shared__ float red[256];
  red[threadIdx.x] = partial;
  __syncthreads();
  for (int off = 128; off > 0; off >>= 1) {
    if (threadIdx.x < (unsigned)off) red[threadIdx.x] += red[threadIdx.x + off];
    __syncthreads();
  }
  if (threadIdx.x == 0) atomicAdd((float*)(ws + OFF_BSUMS) + b, red[0]);
}

__global__ void finalize_kernel(const unsigned int* __restrict__ ws,
                                const float* __restrict__ dx,
                                const float* __restrict__ dy,
                                const float* __restrict__ dth,
                                float* __restrict__ out) {
  if (threadIdx.x == 0 && blockIdx.x == 0) {
    const float* bsums = (const float*)(ws + OFF_BSUMS);
    float s = 0.f;
    for (int b = 0; b < BATCH; ++b) s += bsums[b];
    float align = s / (float)(BATCH * KSEL);
    float r1 = 0.f, r2 = 0.f;
    for (int b = 0; b < BATCH; ++b) {
      r1 += dx[b] * dx[b] + dy[b] * dy[b];
      r2 += dth[b] * dth[b];
    }
    out[0] = align + 0.1f * (r1 / (float)BATCH + r2 / (float)BATCH);
  }
}

extern "C" void kernel_launch(void* const* d_in, const int* in_sizes, int n_in,
                              void* d_out, int out_size, void* d_ws, size_t ws_size,
                              hipStream_t stream) {
  const float* bev   = (const float*)d_in[0];
  const float* prior = (const float*)d_in[1];
  const float* dx    = (const float*)d_in[2];
  const float* dy    = (const float*)d_in[3];
  const float* dth   = (const float*)d_in[4];
  float* out = (float*)d_out;

  unsigned int* ws = (unsigned int*)d_ws;
  float* score   = (float*)ws + OFF_SCORE;
  float* contrib = (float*)ws + OFF_CONTRIB;

  zero_kernel<<<256, 256, 0, stream>>>(ws);
  pixel_stats_kernel<<<(BATCH * HW4 + 255) / 256, 256, 0, stream>>>(bev, prior, score, contrib, ws);
  select_kernel<<<BATCH, 1024, 0, stream>>>(ws, 0);
  hist2_kernel<<<BATCH * SLICES, 256, 0, stream>>>(score, ws);
  select_kernel<<<BATCH, 1024, 0, stream>>>(ws, 1);
  sum_kernel<<<BATCH * SLICES, 256, 0, stream>>>(score, contrib, ws);
  finalize_kernel<<<1, 64, 0, stream>>>(ws, dx, dy, dth, out);
}